// Round 5
// baseline (568.471 us; speedup 1.0000x reference)
//
#include <hip/hip_runtime.h>

// Causal FIR conv via FFT (n_fft = 131072), four-step N = 512 x 256,
// transpose-free, batch-packed (2 real rows -> 1 complex row).
// v9: fwd_cols = v7 math (16(reg) x 32(thread), FFT32 = radix2 x FFT16,
// proven R2) + v8 coalescing (16 n2-lanes fast => 64B runs, proven R4)
// + occupancy fix: 512 threads, 2-round c-split exchange (35 KB LDS),
// twin-redundant readers, <=64 VGPR -> 4 blocks x 8 waves = 32 waves/CU.

#define N_FFT 131072
#define N1    512
#define N2    256
#define T_LEN 65536
#define CB    128
#define PI_F  3.14159265358979323846f
#define R2_F  0.70710678118654752f
#define C16F  0.92387953251128675613f   // cos(pi/8)
#define S16F  0.38268343236508977173f   // sin(pi/8)

typedef __attribute__((ext_vector_type(2))) __fp16 h2;
typedef __attribute__((ext_vector_type(4))) __fp16 h4;
typedef __attribute__((ext_vector_type(8))) __fp16 h8;

__device__ inline int brev9(int x) { return (int)(__brev((unsigned)x) >> 23); }

__device__ inline float2 cadd(float2 a, float2 b){ return make_float2(a.x+b.x, a.y+b.y); }
__device__ inline float2 csub(float2 a, float2 b){ return make_float2(a.x-b.x, a.y-b.y); }
__device__ inline float2 cmul(float2 a, float2 b){ return make_float2(a.x*b.x-a.y*b.y, a.x*b.y+a.y*b.x); }
// a * conj(b)
__device__ inline float2 cmulc(float2 a, float2 b){ return make_float2(a.x*b.x+a.y*b.y, a.y*b.x-a.x*b.y); }
__device__ inline float2 csq(float2 a){ return make_float2(a.x*a.x-a.y*a.y, 2.f*a.x*a.y); }
__device__ inline float2 conjf(float2 a){ return make_float2(a.x, -a.y); }
__device__ inline float2 expif(float a){ float s,c; __sincosf(a,&s,&c); return make_float2(c,s); }
__device__ inline h2 f2h(float2 v){ return __builtin_amdgcn_cvt_pkrtz(v.x, v.y); }

// specialized constant complex multiplies
__device__ inline float2 mul_mi(float2 a){ return make_float2(a.y, -a.x); }                         // * (-i)
__device__ inline float2 mul_pi(float2 a){ return make_float2(-a.y, a.x); }                         // * (+i)
__device__ inline float2 mul_w81(float2 a){ return make_float2(R2_F*(a.x+a.y), R2_F*(a.y-a.x)); }   // * ( r2,-r2)
__device__ inline float2 mul_w83(float2 a){ return make_float2(R2_F*(a.y-a.x), -R2_F*(a.x+a.y)); }  // * (-r2,-r2)
__device__ inline float2 mul_w81c(float2 a){ return make_float2(R2_F*(a.x-a.y), R2_F*(a.x+a.y)); }  // * ( r2, r2)
__device__ inline float2 mul_w83c(float2 a){ return make_float2(-R2_F*(a.x+a.y), R2_F*(a.x-a.y)); } // * (-r2, r2)

// lgkm-only block barrier: don't drain vmcnt (global stores stay in flight)
__device__ __forceinline__ void lgkm_barrier(){
    asm volatile("s_waitcnt lgkmcnt(0)" ::: "memory");
    __builtin_amdgcn_s_barrier();
    __builtin_amdgcn_sched_barrier(0);
}

// Fused DIF double stage (h then h/2). quad (p0, p0+h/2, p0+h, p0+3h/2)
__device__ inline void dif4(float2&a0, float2&a1, float2&a2, float2&a3, float2 w1, float2 w2){
    float2 s02 = cadd(a0,a2), d02 = csub(a0,a2);
    float2 s13 = cadd(a1,a3), d13 = csub(a1,a3);
    float2 b2 = cmul(w1,d02);
    float2 t  = cmul(w1,d13);
    float2 b3 = make_float2(t.y, -t.x);          // -i*t
    a0 = cadd(s02,s13);
    a1 = cmul(w2, csub(s02,s13));
    a2 = cadd(b2,b3);
    a3 = cmul(w2, csub(b2,b3));
}

// Fused DIT double stage (h then 2h), inverse twiddles. quad (p0, p0+h, p0+2h, p0+3h)
__device__ inline void dit4i(float2&a0, float2&a1, float2&a2, float2&a3, float2 w1, float2 w2){
    float2 t1 = cmul(w1,a1), t3 = cmul(w1,a3);
    float2 u0 = cadd(a0,t1), u1 = csub(a0,t1);
    float2 u2 = cadd(a2,t3), u3 = csub(a2,t3);
    float2 s2 = cmul(w2,u2), s3 = cmul(w2,u3);
    a0 = cadd(u0,s2); a2 = csub(u0,s2);
    a1 = make_float2(u1.x - s3.y, u1.y + s3.x);  // u1 + i*s3
    a3 = make_float2(u1.x + s3.y, u1.y - s3.x);  // u1 - i*s3
}

// 4-bit bit-reversal (involution)
__device__ constexpr int BR[16] = {0,8,4,12,2,10,6,14,1,9,5,13,3,11,7,15};

// ---------------------------------------------------------------------------
// FFT-16 fully in registers, forward DIF: natural input, output v[BR[s]]=X[s].
// ---------------------------------------------------------------------------
__device__ __forceinline__ void fft16_fwd(float2 v[16]){
    { // j = 0 (trivial)
        float2 s02=cadd(v[0],v[8]),  d02=csub(v[0],v[8]);
        float2 s13=cadd(v[4],v[12]), d13=csub(v[4],v[12]);
        float2 b3 = mul_mi(d13);
        v[0]=cadd(s02,s13); v[4]=csub(s02,s13);
        v[8]=cadd(d02,b3);  v[12]=csub(d02,b3);
    }
    { // j = 1: w1=(C,-S), w2=W8^1
        float2 s02=cadd(v[1],v[9]),  d02=csub(v[1],v[9]);
        float2 s13=cadd(v[5],v[13]), d13=csub(v[5],v[13]);
        const float2 w1 = make_float2(C16F,-S16F);
        float2 b2 = cmul(w1,d02), b3 = mul_mi(cmul(w1,d13));
        v[1]=cadd(s02,s13);  v[5]=mul_w81(csub(s02,s13));
        v[9]=cadd(b2,b3);    v[13]=mul_w81(csub(b2,b3));
    }
    { // j = 2: w1=W8^1, w2=-i
        float2 s02=cadd(v[2],v[10]), d02=csub(v[2],v[10]);
        float2 s13=cadd(v[6],v[14]), d13=csub(v[6],v[14]);
        float2 b2 = mul_w81(d02), b3 = mul_mi(mul_w81(d13));
        v[2]=cadd(s02,s13);  v[6]=mul_mi(csub(s02,s13));
        v[10]=cadd(b2,b3);   v[14]=mul_mi(csub(b2,b3));
    }
    { // j = 3: w1=(S,-C), w2=W8^3
        float2 s02=cadd(v[3],v[11]), d02=csub(v[3],v[11]);
        float2 s13=cadd(v[7],v[15]), d13=csub(v[7],v[15]);
        const float2 w1 = make_float2(S16F,-C16F);
        float2 b2 = cmul(w1,d02), b3 = mul_mi(cmul(w1,d13));
        v[3]=cadd(s02,s13);  v[7]=mul_w83(csub(s02,s13));
        v[11]=cadd(b2,b3);   v[15]=mul_w83(csub(b2,b3));
    }
#pragma unroll
    for (int q=0;q<4;q++){
        float2 a0=v[4*q],a1=v[4*q+1],a2=v[4*q+2],a3=v[4*q+3];
        float2 s02=cadd(a0,a2), d02=csub(a0,a2);
        float2 s13=cadd(a1,a3), d13=csub(a1,a3);
        float2 b3 = mul_mi(d13);
        v[4*q]=cadd(s02,s13);   v[4*q+1]=csub(s02,s13);
        v[4*q+2]=cadd(d02,b3);  v[4*q+3]=csub(d02,b3);
    }
}

// Same, with v[8..15] == 0 implicit (inputs only v[0..7]); writes all 16.
__device__ __forceinline__ void fft16_fwd_z8(float2 v[16]){
    { // j = 0
        float2 a=v[0], b=v[4];
        float2 ib = mul_mi(b);
        v[0]=cadd(a,b); v[4]=csub(a,b);
        v[8]=cadd(a,ib); v[12]=csub(a,ib);
    }
    { // j = 1
        float2 a=v[1], b=v[5];
        const float2 w1 = make_float2(C16F,-S16F);
        float2 wa = cmul(w1,a), wb = mul_mi(cmul(w1,b));
        v[1]=cadd(a,b);   v[5]=mul_w81(csub(a,b));
        v[9]=cadd(wa,wb); v[13]=mul_w81(csub(wa,wb));
    }
    { // j = 2
        float2 a=v[2], b=v[6];
        float2 wa = mul_w81(a), wb = mul_mi(mul_w81(b));
        v[2]=cadd(a,b);    v[6]=mul_mi(csub(a,b));
        v[10]=cadd(wa,wb); v[14]=mul_mi(csub(wa,wb));
    }
    { // j = 3
        float2 a=v[3], b=v[7];
        const float2 w1 = make_float2(S16F,-C16F);
        float2 wa = cmul(w1,a), wb = mul_mi(cmul(w1,b));
        v[3]=cadd(a,b);    v[7]=mul_w83(csub(a,b));
        v[11]=cadd(wa,wb); v[15]=mul_w83(csub(wa,wb));
    }
#pragma unroll
    for (int q=0;q<4;q++){
        float2 a0=v[4*q],a1=v[4*q+1],a2=v[4*q+2],a3=v[4*q+3];
        float2 s02=cadd(a0,a2), d02=csub(a0,a2);
        float2 s13=cadd(a1,a3), d13=csub(a1,a3);
        float2 b3 = mul_mi(d13);
        v[4*q]=cadd(s02,s13);   v[4*q+1]=csub(s02,s13);
        v[4*q+2]=cadd(d02,b3);  v[4*q+3]=csub(d02,b3);
    }
}

// ---------------------------------------------------------------------------
// Inverse FFT-16 in registers (unnormalized, x16): input v[BR[d]]=F[d],
// natural-order output.
// ---------------------------------------------------------------------------
__device__ __forceinline__ void fft16_inv(float2 v[16]){
#pragma unroll
    for (int q=0;q<4;q++){
        float2 a0=v[4*q],a1=v[4*q+1],a2=v[4*q+2],a3=v[4*q+3];
        float2 u0=cadd(a0,a1), u1=csub(a0,a1);
        float2 u2=cadd(a2,a3), u3=csub(a2,a3);
        v[4*q]=cadd(u0,u2);   v[4*q+2]=csub(u0,u2);
        v[4*q+1]=make_float2(u1.x-u3.y, u1.y+u3.x);
        v[4*q+3]=make_float2(u1.x+u3.y, u1.y-u3.x);
    }
    { // j = 0
        float2 t1=v[4], t3=v[12];
        float2 u0=cadd(v[0],t1), u1=csub(v[0],t1);
        float2 u2=cadd(v[8],t3), u3=csub(v[8],t3);
        v[0]=cadd(u0,u2); v[8]=csub(u0,u2);
        v[4]=make_float2(u1.x-u3.y, u1.y+u3.x);
        v[12]=make_float2(u1.x+u3.y, u1.y-u3.x);
    }
    { // j = 1
        float2 t1=mul_w81c(v[5]), t3=mul_w81c(v[13]);
        float2 u0=cadd(v[1],t1), u1=csub(v[1],t1);
        float2 u2=cadd(v[9],t3), u3=csub(v[9],t3);
        const float2 w2 = make_float2(C16F,S16F);
        float2 s2=cmul(w2,u2), s3=cmul(w2,u3);
        v[1]=cadd(u0,s2); v[9]=csub(u0,s2);
        v[5]=make_float2(u1.x-s3.y, u1.y+s3.x);
        v[13]=make_float2(u1.x+s3.y, u1.y-s3.x);
    }
    { // j = 2
        float2 t1=mul_pi(v[6]), t3=mul_pi(v[14]);
        float2 u0=cadd(v[2],t1), u1=csub(v[2],t1);
        float2 u2=cadd(v[10],t3), u3=csub(v[10],t3);
        float2 s2=mul_w81c(u2), s3=mul_w81c(u3);
        v[2]=cadd(u0,s2); v[10]=csub(u0,s2);
        v[6]=make_float2(u1.x-s3.y, u1.y+s3.x);
        v[14]=make_float2(u1.x+s3.y, u1.y-s3.x);
    }
    { // j = 3
        float2 t1=mul_w83c(v[7]), t3=mul_w83c(v[15]);
        float2 u0=cadd(v[3],t1), u1=csub(v[3],t1);
        float2 u2=cadd(v[11],t3), u3=csub(v[11],t3);
        const float2 w2 = make_float2(S16F,C16F);
        float2 s2=cmul(w2,u2), s3=cmul(w2,u3);
        v[3]=cadd(u0,s2); v[11]=csub(u0,s2);
        v[7]=make_float2(u1.x-s3.y, u1.y+s3.x);
        v[15]=make_float2(u1.x+s3.y, u1.y-s3.x);
    }
}

// ---------------------------------------------------------------------------
// Forward column FFT (512-pt) over n1: 16(reg) x 32(thread) four-step.
// Block: 512 threads = 16 n2-cols (fast, 64B runs) x 32 q. n1 = 32p + q,
// nonzero only p < 8 (n1 < 256).
//   F_q[c] = FFT16_p(x[32p+q])[c]  (fft16_fwd_z8)
//   X[c+16jj+32m] = FFT16_{q1}( radix2_{q0}( W512^{qc} F_q[c] ) )[m]
// Exchange in 2 rounds over c-halves: ex[n2l][cl(8)][q(32)], 35 KB LDS.
// Readers twin-redundant: (clR, jj) role shared by twin pair, m-range split.
// 4 blocks x 8 waves = 32 waves/CU.
// ---------------------------------------------------------------------------
#define FPC 34               // float2 pitch per c (32 q + 2 pad)
#define FPN 274              // float2 pitch per n2 column (8*34 + 2 pad)

template<bool HALF>
__global__ __launch_bounds__(512, 8) void fwd_cols(
    const float* __restrict__ re_base, const float* __restrict__ im_base,
    long long row_stride, void* __restrict__ dstv)
{
    __shared__ __align__(16) float2 s[16 * FPN];   // 35,072 B
    const int tid = threadIdx.x;
    const int tile = blockIdx.x, row = blockIdx.y;
    const int n2base = tile * 16;
    const int n2l = tid & 15, q = tid >> 4;        // q in [0,32)
    const int n2 = n2base + n2l;

    const float* rp = re_base + (long long)row * row_stride;
    const float* ip = im_base ? (im_base + (long long)row * row_stride) : nullptr;

    // ---- phase A: loads (64B runs), FFT16 over p (upper 8 implicit zero)
    float2 v[16];
    if (ip) {
#pragma unroll
        for (int p = 0; p < 8; p++) {
            int g = (32 * p + q) * N2 + n2;
            v[p] = make_float2(rp[g], ip[g]);
        }
    } else {
#pragma unroll
        for (int p = 0; p < 8; p++) {
            int g = (32 * p + q) * N2 + n2;
            v[p] = make_float2(rp[g], 0.f);
        }
    }
    fft16_fwd_z8(v);                               // v[BR[c]] = F_q[c]

    // ---- twiddle W512^{qc}, chained (1 sincos)
    {
        const float2 u = expif((float)q * (-2.f * PI_F / 512.f));
        float2 w = u;
#pragma unroll
        for (int c = 1; c < 16; c++) {
            v[BR[c]] = cmul(v[BR[c]], w);
            if (c < 15) w = cmul(w, u);
        }
    }

    // ---- roles for phase B
    const int cI  = q & 15, jj = q >> 4;           // jj in {0,1}
    const int clR = cI & 7, twin = cI >> 3;        // twin in {0,1}
    const float thN = -2.f * PI_F / (float)N_FFT;
    const float2 stpN = expif(thN * (float)(32 * n2));
    const int exb = n2l * FPN;

#pragma unroll
    for (int h = 0; h < 2; h++) {
        // write c in [8h, 8h+8)
#pragma unroll
        for (int cl = 0; cl < 8; cl++)
            s[exb + cl * FPC + q] = v[BR[8 * h + cl]];
        lgkm_barrier();

        // read row (n2l, clR): radix-2 over q0 (parity jj), FFT16 over q1
        float2 b[16];
        {
            const float4* z4 = (const float4*)(s + exb + clR * FPC);
            if (jj == 0) {
#pragma unroll
                for (int k = 0; k < 8; k++) {
                    float4 A = z4[k], B = z4[k + 8];
                    b[2*k]   = make_float2(A.x + B.x, A.y + B.y);
                    b[2*k+1] = make_float2(A.z + B.z, A.w + B.w);
                }
            } else {
                // W32^{q1} = (cos(pi q1/16), -sin(pi q1/16)), compile-time
                constexpr float CT[16] = {
                    1.f, 0.98078528040323044913f, 0.92387953251128675613f, 0.83146961230254523708f,
                    0.70710678118654752440f, 0.55557023301960222474f, 0.38268343236508977173f,
                    0.19509032201612826785f, 0.f, -0.19509032201612826785f, -0.38268343236508977173f,
                    -0.55557023301960222474f, -0.70710678118654752440f, -0.83146961230254523708f,
                    -0.92387953251128675613f, -0.98078528040323044913f };
                constexpr float ST[16] = {
                    0.f, -0.19509032201612826785f, -0.38268343236508977173f, -0.55557023301960222474f,
                    -0.70710678118654752440f, -0.83146961230254523708f, -0.92387953251128675613f,
                    -0.98078528040323044913f, -1.f, -0.98078528040323044913f, -0.92387953251128675613f,
                    -0.83146961230254523708f, -0.70710678118654752440f, -0.55557023301960222474f,
                    -0.38268343236508977173f, -0.19509032201612826785f };
#pragma unroll
                for (int k = 0; k < 8; k++) {
                    float4 A = z4[k], B = z4[k + 8];
                    float2 d0 = make_float2(A.x - B.x, A.y - B.y);
                    float2 d1 = make_float2(A.z - B.z, A.w - B.w);
                    b[2*k]   = (k == 0) ? d0 : cmul(d0, make_float2(CT[2*k], ST[2*k]));
                    b[2*k+1] = cmul(d1, make_float2(CT[2*k+1], ST[2*k+1]));
                }
            }
        }
        fft16_fwd(b);                              // b[BR[m]] = X[cc+16jj+32m]

        // twin-split stores: m in [8*twin, 8*twin+8), k1 = cc + 16jj + 32m
        const int cc = 8 * h + clR;
        const int k1b = cc + 16 * jj;
        float2 wb = expif(thN * (float)(n2 * (k1b + 256 * twin)));
#pragma unroll
        for (int mm = 0; mm < 8; mm++) {
            int m = 8 * twin + mm;
            float2 rv = cmul(b[BR[m]], wb);
            int k1 = k1b + 32 * m;
            if (HALF) {
                h2* drow = (h2*)dstv + (size_t)row * N_FFT;
                drow[(size_t)k1 * N2 + n2] = f2h(rv);
            } else {
                float2* drow = (float2*)dstv + (size_t)row * N_FFT;
                drow[(size_t)k1 * N2 + n2] = rv;
            }
            if (mm < 7) wb = cmul(wb, stpN);
        }
        if (h == 0) lgkm_barrier();                // reads done -> round 1 writes
    }
}

// ---------------------------------------------------------------------------
// Row-kernel LDS pitch: 18 float2 per 16-point group
// ---------------------------------------------------------------------------
#define RPITCH 18

// ---------------------------------------------------------------------------
// Filter row FFTs: 256-pt forward via 16x16 four-step, FFT-16 in registers.
// Output layout matches mid_rows' register permutation:
//   Ghat[row*256 + 16*t + p] = X[t + 16*BR[p]]
// ---------------------------------------------------------------------------
__global__ __launch_bounds__(128) void fwd_rows_g(float2* __restrict__ G)
{
    __shared__ __align__(16) float2 s[8 * 16 * RPITCH + 16 * RPITCH];
    const int tid = threadIdx.x;
    const int t = tid & 15, rl = tid >> 4;
    const long long row = (long long)blockIdx.x * 8 + rl;
    float2* tab = s + 8 * 16 * RPITCH;

    { // W256^{b*c} table, pitch 18; 128 threads cover 256 entries
        int b0 = tid >> 4, c0 = tid & 15;
        tab[b0 * RPITCH + c0] = expif((float)(b0 * c0) * (-2.f * PI_F / 256.f));
        int e = tid + 128, b1 = e >> 4, c1 = e & 15;
        tab[b1 * RPITCH + c1] = expif((float)(b1 * c1) * (-2.f * PI_F / 256.f));
    }
    __syncthreads();

    const float2* gp = G + (size_t)row * N2 + t;
    float2 v[16];
#pragma unroll
    for (int a = 0; a < 16; a++) v[a] = gp[16 * a];

    fft16_fwd(v);
#pragma unroll
    for (int p = 1; p < 16; p++) v[p] = cmul(v[p], tab[t * RPITCH + BR[p]]);

    float2* rS = s + rl * (16 * RPITCH);
    float4* rS4 = (float4*)rS;
#pragma unroll
    for (int k = 0; k < 8; k++) {
        float2 e = v[BR[2*k]], o = v[BR[2*k] + 8];
        rS4[(t * RPITCH + 2*k) >> 1] = make_float4(e.x, e.y, o.x, o.y);
    }
    asm volatile("s_waitcnt lgkmcnt(0)" ::: "memory");
#pragma unroll
    for (int b = 0; b < 16; b++) v[b] = rS[b * RPITCH + t];

    fft16_fwd(v);

    float4* o4 = (float4*)(G + (size_t)row * N2 + 16 * t);
#pragma unroll
    for (int m = 0; m < 8; m++)
        o4[m] = make_float4(v[2*m].x, v[2*m].y, v[2*m+1].x, v[2*m+1].y);
}

// ---------------------------------------------------------------------------
// Fused mid: fwd row FFT -> x Ghat -> inv row FFT -> conj big twiddle.
// 16x16 four-step, FFT-16 in registers; intra-wave exchange, one barrier.
// ---------------------------------------------------------------------------
__global__ __launch_bounds__(256, 4) void mid_rows(
    h2* __restrict__ buf, const float2* __restrict__ Gh)
{
    __shared__ __align__(16) float2 s[16 * 16 * RPITCH + 16 * RPITCH];
    const int tid = threadIdx.x;
    const int t = tid & 15, rl = tid >> 4;
    const long long row = (long long)blockIdx.x * 16 + rl;
    const int k1 = (int)(row & (N1 - 1));
    float2* tab = s + 16 * 16 * RPITCH;

    { // W256^{b*c} table
        int b = tid >> 4, c = tid & 15;
        tab[b * RPITCH + c] = expif((float)(b * c) * (-2.f * PI_F / 256.f));
    }
    __syncthreads();                              // the only barrier

    h2* bp = buf + ((size_t)row * N2 + t);
    float2 v[16];
#pragma unroll
    for (int a = 0; a < 16; a++) {
        h2 h = bp[16 * a];
        v[a] = make_float2((float)h.x, (float)h.y);
    }

    fft16_fwd(v);
#pragma unroll
    for (int p = 1; p < 16; p++) v[p] = cmul(v[p], tab[t * RPITCH + BR[p]]);

    float2* rS = s + rl * (16 * RPITCH);
    float4* rS4 = (float4*)rS;
#pragma unroll
    for (int k = 0; k < 8; k++) {
        float2 e = v[BR[2*k]], o = v[BR[2*k] + 8];
        rS4[(t * RPITCH + 2*k) >> 1] = make_float4(e.x, e.y, o.x, o.y);
    }

    const float4* g4 = (const float4*)(Gh + ((size_t)k1 * N2 + 16 * t));
    float4 g[8];
#pragma unroll
    for (int m = 0; m < 8; m++) g[m] = g4[m];

    asm volatile("s_waitcnt lgkmcnt(0)" ::: "memory");
#pragma unroll
    for (int b = 0; b < 16; b++) v[b] = rS[b * RPITCH + t];

    fft16_fwd(v);

#pragma unroll
    for (int m = 0; m < 8; m++) {
        v[2*m]   = cmul(v[2*m],   make_float2(g[m].x, g[m].y));
        v[2*m+1] = cmul(v[2*m+1], make_float2(g[m].z, g[m].w));
    }

    fft16_inv(v);
#pragma unroll
    for (int b = 1; b < 16; b++) v[b] = cmulc(v[b], tab[b * RPITCH + t]);

#pragma unroll
    for (int m = 0; m < 8; m++)
        rS4[(t * RPITCH + 2*m) >> 1] = make_float4(v[2*m].x, v[2*m].y, v[2*m+1].x, v[2*m+1].y);
    asm volatile("s_waitcnt lgkmcnt(0)" ::: "memory");
#pragma unroll
    for (int c = 0; c < 16; c++) v[BR[c]] = rS[c * RPITCH + t];

    fft16_inv(v);

    {
        const float th = 2.f * PI_F / (float)N_FFT;
        float2 w = expif((float)(k1 * t) * th);
        const float2 stp = expif((float)(16 * k1) * th);
#pragma unroll
        for (int a = 0; a < 16; a++) {
            float2 r = cmul(v[a], w);
            bp[16 * a] = f2h(r);
            if (a < 15) w = cmul(w, stp);
        }
    }
}

// ---------------------------------------------------------------------------
// Inverse column FFT (512-pt DIT, brev load) over k1, scale, keep n1<256.
// ---------------------------------------------------------------------------
__global__ __launch_bounds__(512, 4) void inv_cols(
    const h2* __restrict__ src, float* __restrict__ out)
{
    __shared__ float4 s4[N1 * 16 / 2];            // 64 KB
    float2* s = (float2*)s4;
    const int tile = blockIdx.x, row = blockIdx.y, tid = threadIdx.x;
    const int n2base = tile * 16;
    const h2* srow = src + (size_t)row * N_FFT;
    const int cp = tid & 7, r8 = tid >> 3;        // r8 in [0,64)

#pragma unroll
    for (int i = 0; i < 8; i++) {
        int k1 = r8 + 64 * i;
        h4 v = *((const h4*)(srow + (size_t)k1 * N2 + n2base + 2 * cp));
        int p = brev9(k1);
        s4[p * 8 + cp] = make_float4((float)v.x, (float)v.y, (float)v.z, (float)v.w);
    }
    __syncthreads();

    const int c = tid & 15, r = tid >> 4;         // r in [0,32)

    const float2 w1c = make_float2(0.f, 1.f);     // conj(W_4^1) = i
    const float2 w2c = make_float2(R2_F, R2_F);   // conj(W_8^1)
    const float2 one = make_float2(1.f, 0.f);
#pragma unroll
    for (int o = 0; o < 2; o++) {
        int base = 8 * (r + 32 * o);
        float2 v[8];
#pragma unroll
        for (int m = 0; m < 8; m++) v[m] = s[(base + m) * 16 + c];
#pragma unroll
        for (int m = 0; m < 8; m += 2) {
            float2 a = v[m], b = v[m + 1];
            v[m] = cadd(a, b); v[m + 1] = csub(a, b);
        }
        dit4i(v[0], v[2], v[4], v[6], one, one);
        dit4i(v[1], v[3], v[5], v[7], w1c, w2c);
#pragma unroll
        for (int m = 0; m < 8; m++) s[(base + m) * 16 + c] = v[m];
    }
    __syncthreads();

    {
        float2 w2 = expif((float)(r & 7) * (PI_F / 16.f));
        float2 w1 = csq(w2);
#pragma unroll
        for (int qq = 0; qq < 4; qq++) {
            int g = (r >> 3) + 4 * qq;
            int p0 = g * 32 + (r & 7);
            float2 a0 = s[p0*16+c], a1 = s[(p0+8)*16+c], a2 = s[(p0+16)*16+c], a3 = s[(p0+24)*16+c];
            dit4i(a0, a1, a2, a3, w1, w2);
            s[p0*16+c] = a0; s[(p0+8)*16+c] = a1; s[(p0+16)*16+c] = a2; s[(p0+24)*16+c] = a3;
        }
    }
    __syncthreads();
    {
        float2 w2 = expif((float)r * (PI_F / 64.f));
        float2 w1 = csq(w2);
#pragma unroll
        for (int qq = 0; qq < 4; qq++) {
            int p0 = qq * 128 + r;
            float2 a0 = s[p0*16+c], a1 = s[(p0+32)*16+c], a2 = s[(p0+64)*16+c], a3 = s[(p0+96)*16+c];
            dit4i(a0, a1, a2, a3, w1, w2);
            s[p0*16+c] = a0; s[(p0+32)*16+c] = a1; s[(p0+64)*16+c] = a2; s[(p0+96)*16+c] = a3;
        }
    }
    __syncthreads();
    {
        float2 w2 = expif((float)r * (PI_F / 256.f));
        const float2 stp = make_float2(0.92387953251f, 0.38268343236f);
#pragma unroll
        for (int qq = 0; qq < 4; qq++) {
            int j = r + 32 * qq;
            float2 w1 = csq(w2);
            float2 a0 = s[j*16+c], a1 = s[(j+128)*16+c], a2 = s[(j+256)*16+c], a3 = s[(j+384)*16+c];
            dit4i(a0, a1, a2, a3, w1, w2);
            s[j*16+c] = a0; s[(j+128)*16+c] = a1; s[(j+256)*16+c] = a2; s[(j+384)*16+c] = a3;
            w2 = cmul(w2, stp);
        }
    }
    __syncthreads();

    const float scale = 1.0f / (float)N_FFT;
    float* out0 = out + (size_t)(2 * row) * T_LEN;
    float* out1 = out + (size_t)(2 * row + 1) * T_LEN;
#pragma unroll
    for (int i = 0; i < 4; i++) {
        int p = r8 + 64 * i;                      // p < 256
        float4 q = s4[p * 8 + cp];
        int n = p * N2 + n2base + 2 * cp;
        *(float2*)(out0 + n) = make_float2(q.x * scale, q.z * scale);
        *(float2*)(out1 + n) = make_float2(q.y * scale, q.w * scale);
    }
}

extern "C" void kernel_launch(void* const* d_in, const int* in_sizes, int n_in,
                              void* d_out, int out_size, void* d_ws, size_t ws_size,
                              hipStream_t stream) {
    const float* x    = (const float*)d_in[0];
    const float* filt = (const float*)d_in[1];
    float* out = (float*)d_out;

    h2* buf = (h2*)d_ws;                                                        // 67 MB
    float2* G = (float2*)((char*)d_ws + (size_t)CB * N_FFT * sizeof(h2));       // 1 MB

    fwd_cols<false><<<dim3(16, 1), 512, 0, stream>>>(filt, nullptr, 0LL, (void*)G);
    fwd_rows_g<<<N1 / 8, 128, 0, stream>>>(G);
    fwd_cols<true><<<dim3(16, CB), 512, 0, stream>>>(x, x + T_LEN, (long long)(2 * T_LEN), (void*)buf);
    mid_rows<<<(CB * N1) / 16, 256, 0, stream>>>(buf, G);
    inv_cols<<<dim3(16, CB), 512, 0, stream>>>(buf, out);
}

// Round 7
// 220.980 us; speedup vs baseline: 2.5725x; 2.5725x over previous
//
#include <hip/hip_runtime.h>

// Causal FIR conv via FFT (n_fft = 131072), four-step N = 512 x 256,
// transpose-free, batch-packed (2 real rows -> 1 complex row).
// v11 = v8 (proven 224 us, tripwire-clean) + inv_cols ported to the same
// 32(reg) x 16(thread) register-FFT structure as fwd_cols:
//   A_r[q] = invFFT16_s Z[r+32s]; B_q[r] = W512^{-qr} A_r[q];
//   y[16p+q] = invFFT16_t(B[2t])[p] + W32^{-p} invFFT16_t(B[2t+1])[p].
// 2-round exchange (37 KB LDS, 3 lgkm-only barriers), 64B-coalesced loads
// and stores, compile-time W32^{-p}. fwd_cols/mid_rows/fwd_rows_g untouched.

#define N_FFT 131072
#define N1    512
#define N2    256
#define T_LEN 65536
#define CB    128
#define PI_F  3.14159265358979323846f
#define R2_F  0.70710678118654752f
#define C16F  0.92387953251128675613f   // cos(pi/8)
#define S16F  0.38268343236508977173f   // sin(pi/8)

typedef __attribute__((ext_vector_type(2))) __fp16 h2;
typedef __attribute__((ext_vector_type(4))) __fp16 h4;
typedef __attribute__((ext_vector_type(8))) __fp16 h8;

__device__ inline int brev9(int x) { return (int)(__brev((unsigned)x) >> 23); }

__device__ inline float2 cadd(float2 a, float2 b){ return make_float2(a.x+b.x, a.y+b.y); }
__device__ inline float2 csub(float2 a, float2 b){ return make_float2(a.x-b.x, a.y-b.y); }
__device__ inline float2 cmul(float2 a, float2 b){ return make_float2(a.x*b.x-a.y*b.y, a.x*b.y+a.y*b.x); }
// a * conj(b)
__device__ inline float2 cmulc(float2 a, float2 b){ return make_float2(a.x*b.x+a.y*b.y, a.y*b.x-a.x*b.y); }
__device__ inline float2 csq(float2 a){ return make_float2(a.x*a.x-a.y*a.y, 2.f*a.x*a.y); }
__device__ inline float2 conjf(float2 a){ return make_float2(a.x, -a.y); }
__device__ inline float2 expif(float a){ float s,c; __sincosf(a,&s,&c); return make_float2(c,s); }
__device__ inline h2 f2h(float2 v){ return __builtin_amdgcn_cvt_pkrtz(v.x, v.y); }

// specialized constant complex multiplies
__device__ inline float2 mul_mi(float2 a){ return make_float2(a.y, -a.x); }                         // * (-i)
__device__ inline float2 mul_pi(float2 a){ return make_float2(-a.y, a.x); }                         // * (+i)
__device__ inline float2 mul_w81(float2 a){ return make_float2(R2_F*(a.x+a.y), R2_F*(a.y-a.x)); }   // * ( r2,-r2)
__device__ inline float2 mul_w83(float2 a){ return make_float2(R2_F*(a.y-a.x), -R2_F*(a.x+a.y)); }  // * (-r2,-r2)
__device__ inline float2 mul_w81c(float2 a){ return make_float2(R2_F*(a.x-a.y), R2_F*(a.x+a.y)); }  // * ( r2, r2)
__device__ inline float2 mul_w83c(float2 a){ return make_float2(-R2_F*(a.x+a.y), R2_F*(a.x-a.y)); } // * (-r2, r2)

// lgkm-only block barrier: don't drain vmcnt (global stores stay in flight)
__device__ __forceinline__ void lgkm_barrier(){
    asm volatile("s_waitcnt lgkmcnt(0)" ::: "memory");
    __builtin_amdgcn_s_barrier();
    __builtin_amdgcn_sched_barrier(0);
}

// 4-bit bit-reversal (involution)
__device__ constexpr int BR[16] = {0,8,4,12,2,10,6,14,1,9,5,13,3,11,7,15};

// ---------------------------------------------------------------------------
// FFT-16 fully in registers, forward DIF: natural input, output v[BR[s]]=X[s].
// ---------------------------------------------------------------------------
__device__ __forceinline__ void fft16_fwd(float2 v[16]){
    { // j = 0 (trivial)
        float2 s02=cadd(v[0],v[8]),  d02=csub(v[0],v[8]);
        float2 s13=cadd(v[4],v[12]), d13=csub(v[4],v[12]);
        float2 b3 = mul_mi(d13);
        v[0]=cadd(s02,s13); v[4]=csub(s02,s13);
        v[8]=cadd(d02,b3);  v[12]=csub(d02,b3);
    }
    { // j = 1: w1=(C,-S), w2=W8^1
        float2 s02=cadd(v[1],v[9]),  d02=csub(v[1],v[9]);
        float2 s13=cadd(v[5],v[13]), d13=csub(v[5],v[13]);
        const float2 w1 = make_float2(C16F,-S16F);
        float2 b2 = cmul(w1,d02), b3 = mul_mi(cmul(w1,d13));
        v[1]=cadd(s02,s13);  v[5]=mul_w81(csub(s02,s13));
        v[9]=cadd(b2,b3);    v[13]=mul_w81(csub(b2,b3));
    }
    { // j = 2: w1=W8^1, w2=-i
        float2 s02=cadd(v[2],v[10]), d02=csub(v[2],v[10]);
        float2 s13=cadd(v[6],v[14]), d13=csub(v[6],v[14]);
        float2 b2 = mul_w81(d02), b3 = mul_mi(mul_w81(d13));
        v[2]=cadd(s02,s13);  v[6]=mul_mi(csub(s02,s13));
        v[10]=cadd(b2,b3);   v[14]=mul_mi(csub(b2,b3));
    }
    { // j = 3: w1=(S,-C), w2=W8^3
        float2 s02=cadd(v[3],v[11]), d02=csub(v[3],v[11]);
        float2 s13=cadd(v[7],v[15]), d13=csub(v[7],v[15]);
        const float2 w1 = make_float2(S16F,-C16F);
        float2 b2 = cmul(w1,d02), b3 = mul_mi(cmul(w1,d13));
        v[3]=cadd(s02,s13);  v[7]=mul_w83(csub(s02,s13));
        v[11]=cadd(b2,b3);   v[15]=mul_w83(csub(b2,b3));
    }
#pragma unroll
    for (int q=0;q<4;q++){
        float2 a0=v[4*q],a1=v[4*q+1],a2=v[4*q+2],a3=v[4*q+3];
        float2 s02=cadd(a0,a2), d02=csub(a0,a2);
        float2 s13=cadd(a1,a3), d13=csub(a1,a3);
        float2 b3 = mul_mi(d13);
        v[4*q]=cadd(s02,s13);   v[4*q+1]=csub(s02,s13);
        v[4*q+2]=cadd(d02,b3);  v[4*q+3]=csub(d02,b3);
    }
}

// ---------------------------------------------------------------------------
// Inverse FFT-16 in registers (unnormalized, x16): input v[BR[d]]=F[d],
// natural-order output.
// ---------------------------------------------------------------------------
__device__ __forceinline__ void fft16_inv(float2 v[16]){
#pragma unroll
    for (int q=0;q<4;q++){
        float2 a0=v[4*q],a1=v[4*q+1],a2=v[4*q+2],a3=v[4*q+3];
        float2 u0=cadd(a0,a1), u1=csub(a0,a1);
        float2 u2=cadd(a2,a3), u3=csub(a2,a3);
        v[4*q]=cadd(u0,u2);   v[4*q+2]=csub(u0,u2);
        v[4*q+1]=make_float2(u1.x-u3.y, u1.y+u3.x);
        v[4*q+3]=make_float2(u1.x+u3.y, u1.y-u3.x);
    }
    { // j = 0
        float2 t1=v[4], t3=v[12];
        float2 u0=cadd(v[0],t1), u1=csub(v[0],t1);
        float2 u2=cadd(v[8],t3), u3=csub(v[8],t3);
        v[0]=cadd(u0,u2); v[8]=csub(u0,u2);
        v[4]=make_float2(u1.x-u3.y, u1.y+u3.x);
        v[12]=make_float2(u1.x+u3.y, u1.y-u3.x);
    }
    { // j = 1
        float2 t1=mul_w81c(v[5]), t3=mul_w81c(v[13]);
        float2 u0=cadd(v[1],t1), u1=csub(v[1],t1);
        float2 u2=cadd(v[9],t3), u3=csub(v[9],t3);
        const float2 w2 = make_float2(C16F,S16F);
        float2 s2=cmul(w2,u2), s3=cmul(w2,u3);
        v[1]=cadd(u0,s2); v[9]=csub(u0,s2);
        v[5]=make_float2(u1.x-s3.y, u1.y+s3.x);
        v[13]=make_float2(u1.x+s3.y, u1.y-s3.x);
    }
    { // j = 2
        float2 t1=mul_pi(v[6]), t3=mul_pi(v[14]);
        float2 u0=cadd(v[2],t1), u1=csub(v[2],t1);
        float2 u2=cadd(v[10],t3), u3=csub(v[10],t3);
        float2 s2=mul_w81c(u2), s3=mul_w81c(u3);
        v[2]=cadd(u0,s2); v[10]=csub(u0,s2);
        v[6]=make_float2(u1.x-s3.y, u1.y+s3.x);
        v[14]=make_float2(u1.x+s3.y, u1.y-s3.x);
    }
    { // j = 3
        float2 t1=mul_w83c(v[7]), t3=mul_w83c(v[15]);
        float2 u0=cadd(v[3],t1), u1=csub(v[3],t1);
        float2 u2=cadd(v[11],t3), u3=csub(v[11],t3);
        const float2 w2 = make_float2(S16F,C16F);
        float2 s2=cmul(w2,u2), s3=cmul(w2,u3);
        v[3]=cadd(u0,s2); v[11]=csub(u0,s2);
        v[7]=make_float2(u1.x-s3.y, u1.y+s3.x);
        v[15]=make_float2(u1.x+s3.y, u1.y-s3.x);
    }
}

// ---------------------------------------------------------------------------
// Forward column FFT (512-pt) over n1: 32(reg) x 16(thread) four-step.
// Block: 256 threads = 16 n2-cols (fast) x 16 q. n1 = 16p + q; input nonzero
// only n1 < 256 <=> p < 16. FFT32 over p with zero half = 2x FFT16:
//   F_q[2t] = FFT16(x)[t], F_q[2t+1] = FFT16(x * W32^p)[t].
// X[r + 32 s] = FFT16_q( W512^{qr} F_q[r] )[s]; store k1 = r + 32 s.
// Exchange in 2 rounds over r-halves: ex[n2l][rl(16)][q(16)], pitches 290/18/1.
// ---------------------------------------------------------------------------
template<bool HALF>
__global__ __launch_bounds__(256, 4) void fwd_cols(
    const float* __restrict__ re_base, const float* __restrict__ im_base,
    long long row_stride, void* __restrict__ dstv)
{
    __shared__ __align__(16) float2 s[16 * 290];   // 37,120 B
    const int tid = threadIdx.x;
    const int tile = blockIdx.x, row = blockIdx.y;
    const int n2base = tile * 16;
    const int n2l = tid & 15, q = tid >> 4;        // both in [0,16)
    const int n2 = n2base + n2l;

    const float* rp = re_base + (long long)row * row_stride;
    const float* ip = im_base ? (im_base + (long long)row * row_stride) : nullptr;

    // ---- phase A: loads (64B runs), two FFT16s
    float2 vE[16], vO[16];
    if (ip) {
#pragma unroll
        for (int p = 0; p < 16; p++) {
            int g = (16 * p + q) * N2 + n2;
            vE[p] = make_float2(rp[g], ip[g]);
        }
    } else {
#pragma unroll
        for (int p = 0; p < 16; p++) {
            int g = (16 * p + q) * N2 + n2;
            vE[p] = make_float2(rp[g], 0.f);
        }
    }
    { // vO = x * W32^p, W32^p = (cos(pi p/16), -sin(pi p/16)) compile-time
        constexpr float WC[16] = {
            1.f, 0.98078528040323044913f, 0.92387953251128675613f, 0.83146961230254523708f,
            0.70710678118654752440f, 0.55557023301960222474f, 0.38268343236508977173f,
            0.19509032201612826785f, 0.f, -0.19509032201612826785f, -0.38268343236508977173f,
            -0.55557023301960222474f, -0.70710678118654752440f, -0.83146961230254523708f,
            -0.92387953251128675613f, -0.98078528040323044913f };
        constexpr float WS[16] = {
            0.f, -0.19509032201612826785f, -0.38268343236508977173f, -0.55557023301960222474f,
            -0.70710678118654752440f, -0.83146961230254523708f, -0.92387953251128675613f,
            -0.98078528040323044913f, -1.f, -0.98078528040323044913f, -0.92387953251128675613f,
            -0.83146961230254523708f, -0.70710678118654752440f, -0.55557023301960222474f,
            -0.38268343236508977173f, -0.19509032201612826785f };
        vO[0] = vE[0];
#pragma unroll
        for (int p = 1; p < 16; p++) vO[p] = cmul(vE[p], make_float2(WC[p], WS[p]));
    }
    fft16_fwd(vE);                                 // vE[BR[t]] = F_q[2t]
    fft16_fwd(vO);                                 // vO[BR[t]] = F_q[2t+1]

    // ---- exchange twiddle chain: w = W512^{q*r}, u = W512^{q}
    const float2 u = expif((float)q * (-2.f * PI_F / 512.f));
    float2 w = make_float2(1.f, 0.f);
    const int exbase = n2l * 290;
    const float thN = -2.f * PI_F / (float)N_FFT;
    const float2 stpN = expif(thN * (float)(32 * n2));

#pragma unroll
    for (int h = 0; h < 2; h++) {
        // write round h: r = 16h + rl, rl in [0,16); w chained = W512^{qr}
#pragma unroll
        for (int t = 0; t < 8; t++) {
            int tt = t + 8 * h;                    // r = 2*tt, 2*tt+1
            int rl = 2 * t;
            s[exbase + rl * 18 + q]       = cmul(vE[BR[tt]], w);  w = cmul(w, u);
            s[exbase + (rl + 1) * 18 + q] = cmul(vO[BR[tt]], w);  w = cmul(w, u);
        }
        lgkm_barrier();

        // read round h: this thread owns r' = 16h + q
        float2 b[16];
        {
            const float4* z4 = (const float4*)(s + exbase + q * 18);
#pragma unroll
            for (int j = 0; j < 8; j++) {
                float4 A = z4[j];
                b[2*j]   = make_float2(A.x, A.y);
                b[2*j+1] = make_float2(A.z, A.w);
            }
        }
        fft16_fwd(b);                              // b[BR[s]] = X[r' + 32 s]

        // big twiddle W_N^{n2*k1}, k1 = r' + 32 m (chained), store
        const int rpr = 16 * h + q;
        float2 wb = expif(thN * (float)(n2 * rpr));
#pragma unroll
        for (int m = 0; m < 16; m++) {
            float2 rv = cmul(b[BR[m]], wb);
            int k1 = rpr + 32 * m;
            if (HALF) {
                h2* drow = (h2*)dstv + (size_t)row * N_FFT;
                drow[(size_t)k1 * N2 + n2] = f2h(rv);
            } else {
                float2* drow = (float2*)dstv + (size_t)row * N_FFT;
                drow[(size_t)k1 * N2 + n2] = rv;
            }
            if (m < 15) wb = cmul(wb, stpN);
        }
        if (h == 0) lgkm_barrier();                // reads done -> round 1 writes
    }
}

// ---------------------------------------------------------------------------
// Row-kernel LDS pitch: 18 float2 per 16-point group
// ---------------------------------------------------------------------------
#define RPITCH 18

// ---------------------------------------------------------------------------
// Filter row FFTs: 256-pt forward via 16x16 four-step, FFT-16 in registers.
// Output layout matches mid_rows' register permutation:
//   Ghat[row*256 + 16*t + p] = X[t + 16*BR[p]]
// ---------------------------------------------------------------------------
__global__ __launch_bounds__(128) void fwd_rows_g(float2* __restrict__ G)
{
    __shared__ __align__(16) float2 s[8 * 16 * RPITCH + 16 * RPITCH];
    const int tid = threadIdx.x;
    const int t = tid & 15, rl = tid >> 4;
    const long long row = (long long)blockIdx.x * 8 + rl;
    float2* tab = s + 8 * 16 * RPITCH;

    { // W256^{b*c} table, pitch 18; 128 threads cover 256 entries
        int b0 = tid >> 4, c0 = tid & 15;
        tab[b0 * RPITCH + c0] = expif((float)(b0 * c0) * (-2.f * PI_F / 256.f));
        int e = tid + 128, b1 = e >> 4, c1 = e & 15;
        tab[b1 * RPITCH + c1] = expif((float)(b1 * c1) * (-2.f * PI_F / 256.f));
    }
    __syncthreads();

    const float2* gp = G + (size_t)row * N2 + t;
    float2 v[16];
#pragma unroll
    for (int a = 0; a < 16; a++) v[a] = gp[16 * a];

    fft16_fwd(v);
#pragma unroll
    for (int p = 1; p < 16; p++) v[p] = cmul(v[p], tab[t * RPITCH + BR[p]]);

    float2* rS = s + rl * (16 * RPITCH);
    float4* rS4 = (float4*)rS;
#pragma unroll
    for (int k = 0; k < 8; k++) {
        float2 e = v[BR[2*k]], o = v[BR[2*k] + 8];
        rS4[(t * RPITCH + 2*k) >> 1] = make_float4(e.x, e.y, o.x, o.y);
    }
    asm volatile("s_waitcnt lgkmcnt(0)" ::: "memory");
#pragma unroll
    for (int b = 0; b < 16; b++) v[b] = rS[b * RPITCH + t];

    fft16_fwd(v);

    float4* o4 = (float4*)(G + (size_t)row * N2 + 16 * t);
#pragma unroll
    for (int m = 0; m < 8; m++)
        o4[m] = make_float4(v[2*m].x, v[2*m].y, v[2*m+1].x, v[2*m+1].y);
}

// ---------------------------------------------------------------------------
// Fused mid: fwd row FFT -> x Ghat -> inv row FFT -> conj big twiddle.
// 16x16 four-step, FFT-16 in registers; intra-wave exchange, one barrier.
// ---------------------------------------------------------------------------
__global__ __launch_bounds__(256, 4) void mid_rows(
    h2* __restrict__ buf, const float2* __restrict__ Gh)
{
    __shared__ __align__(16) float2 s[16 * 16 * RPITCH + 16 * RPITCH];
    const int tid = threadIdx.x;
    const int t = tid & 15, rl = tid >> 4;
    const long long row = (long long)blockIdx.x * 16 + rl;
    const int k1 = (int)(row & (N1 - 1));
    float2* tab = s + 16 * 16 * RPITCH;

    { // W256^{b*c} table
        int b = tid >> 4, c = tid & 15;
        tab[b * RPITCH + c] = expif((float)(b * c) * (-2.f * PI_F / 256.f));
    }
    __syncthreads();                              // the only barrier

    h2* bp = buf + ((size_t)row * N2 + t);
    float2 v[16];
#pragma unroll
    for (int a = 0; a < 16; a++) {
        h2 h = bp[16 * a];
        v[a] = make_float2((float)h.x, (float)h.y);
    }

    fft16_fwd(v);
#pragma unroll
    for (int p = 1; p < 16; p++) v[p] = cmul(v[p], tab[t * RPITCH + BR[p]]);

    float2* rS = s + rl * (16 * RPITCH);
    float4* rS4 = (float4*)rS;
#pragma unroll
    for (int k = 0; k < 8; k++) {
        float2 e = v[BR[2*k]], o = v[BR[2*k] + 8];
        rS4[(t * RPITCH + 2*k) >> 1] = make_float4(e.x, e.y, o.x, o.y);
    }

    const float4* g4 = (const float4*)(Gh + ((size_t)k1 * N2 + 16 * t));
    float4 g[8];
#pragma unroll
    for (int m = 0; m < 8; m++) g[m] = g4[m];

    asm volatile("s_waitcnt lgkmcnt(0)" ::: "memory");
#pragma unroll
    for (int b = 0; b < 16; b++) v[b] = rS[b * RPITCH + t];

    fft16_fwd(v);

#pragma unroll
    for (int m = 0; m < 8; m++) {
        v[2*m]   = cmul(v[2*m],   make_float2(g[m].x, g[m].y));
        v[2*m+1] = cmul(v[2*m+1], make_float2(g[m].z, g[m].w));
    }

    fft16_inv(v);
#pragma unroll
    for (int b = 1; b < 16; b++) v[b] = cmulc(v[b], tab[b * RPITCH + t]);

#pragma unroll
    for (int m = 0; m < 8; m++)
        rS4[(t * RPITCH + 2*m) >> 1] = make_float4(v[2*m].x, v[2*m].y, v[2*m+1].x, v[2*m+1].y);
    asm volatile("s_waitcnt lgkmcnt(0)" ::: "memory");
#pragma unroll
    for (int c = 0; c < 16; c++) v[BR[c]] = rS[c * RPITCH + t];

    fft16_inv(v);

    {
        const float th = 2.f * PI_F / (float)N_FFT;
        float2 w = expif((float)(k1 * t) * th);
        const float2 stp = expif((float)(16 * k1) * th);
#pragma unroll
        for (int a = 0; a < 16; a++) {
            float2 r = cmul(v[a], w);
            bp[16 * a] = f2h(r);
            if (a < 15) w = cmul(w, stp);
        }
    }
}

// ---------------------------------------------------------------------------
// Inverse column FFT (512-pt) over k1: 32(reg) x 16(thread) four-step.
// Block: 256 threads = 16 n2-cols (fast) x 16 u. k1 = r + 32 s.
//   A_r[q] = invFFT16_s Z[r+32s]          (thread u handles r = u, u+16)
//   B_q[r] = W512^{-qr} A_r[q]
//   y[16p+q] = invFFT16_t(B[2t])[p] + W32^{-p} invFFT16_t(B[2t+1])[p], p<16
// Exchange in 2 rounds over r-halves: ex[n2l][q(16)*18 + rl], 37 KB LDS.
// Scale 1/N_FFT; unpack packed complex to rows 2row / 2row+1.
// ---------------------------------------------------------------------------
__global__ __launch_bounds__(256, 4) void inv_cols(
    const h2* __restrict__ src, float* __restrict__ out)
{
    __shared__ __align__(16) float2 s[16 * 290];   // 37,120 B
    const int tid = threadIdx.x;
    const int tile = blockIdx.x, row = blockIdx.y;
    const int n2base = tile * 16;
    const int n2l = tid & 15, u = tid >> 4;        // both in [0,16)
    const int n2 = n2base + n2l;
    const h2* srow = src + (size_t)row * N_FFT;

    // ---- phase A: loads (64B runs), invFFT16 over s for r = u and r = u+16
    float2 vA[16], vB[16];
#pragma unroll
    for (int ss = 0; ss < 16; ss++) {
        h2 a = srow[(size_t)(u + 32 * ss) * N2 + n2];
        vA[BR[ss]] = make_float2((float)a.x, (float)a.y);
    }
#pragma unroll
    for (int ss = 0; ss < 16; ss++) {
        h2 a = srow[(size_t)(u + 16 + 32 * ss) * N2 + n2];
        vB[BR[ss]] = make_float2((float)a.x, (float)a.y);
    }
    fft16_inv(vA);                                 // vA[q] = A_u[q]
    fft16_inv(vB);                                 // vB[q] = A_{u+16}[q]

    // ---- twiddle B_q[r] = W512^{-qr} A_r[q], chained over q (2 sincos)
    {
        const float2 e1 = expif((float)u        * (2.f * PI_F / 512.f));
        const float2 e2 = expif((float)(u + 16) * (2.f * PI_F / 512.f));
        float2 w1 = e1, w2 = e2;
#pragma unroll
        for (int qq = 1; qq < 16; qq++) {
            vA[qq] = cmul(vA[qq], w1);
            vB[qq] = cmul(vB[qq], w2);
            if (qq < 15) { w1 = cmul(w1, e1); w2 = cmul(w2, e2); }
        }
    }

    const int exb = n2l * 290;
    float2 bE[16], bO[16];

    // ---- round 0: write column r = u (rows q), read row q = u (cols rl = r)
#pragma unroll
    for (int qq = 0; qq < 16; qq++)
        s[exb + qq * 18 + u] = vA[qq];
    lgkm_barrier();
    {
        const float4* z4 = (const float4*)(s + exb + u * 18);
#pragma unroll
        for (int j = 0; j < 8; j++) {
            float4 A = z4[j];                      // B[2j], B[2j+1]
            bE[BR[j]] = make_float2(A.x, A.y);
            bO[BR[j]] = make_float2(A.z, A.w);
        }
    }
    lgkm_barrier();                                // reads done -> round 1 writes

    // ---- round 1: write column r = u+16, read r = 16..31
#pragma unroll
    for (int qq = 0; qq < 16; qq++)
        s[exb + qq * 18 + u] = vB[qq];
    lgkm_barrier();
    {
        const float4* z4 = (const float4*)(s + exb + u * 18);
#pragma unroll
        for (int j = 0; j < 8; j++) {
            float4 A = z4[j];                      // B[16+2j], B[16+2j+1]
            bE[BR[8 + j]] = make_float2(A.x, A.y);
            bO[BR[8 + j]] = make_float2(A.z, A.w);
        }
    }

    fft16_inv(bE);                                 // E[p], natural p
    fft16_inv(bO);                                 // O[p]

    // ---- y[16p+u] = (E[p] + W32^{-p} O[p]) / N_FFT; 64B-run stores
    {
        // W32^{-p} = (cos(pi p/16), +sin(pi p/16)), compile-time
        constexpr float WCI[16] = {
            1.f, 0.98078528040323044913f, 0.92387953251128675613f, 0.83146961230254523708f,
            0.70710678118654752440f, 0.55557023301960222474f, 0.38268343236508977173f,
            0.19509032201612826785f, 0.f, -0.19509032201612826785f, -0.38268343236508977173f,
            -0.55557023301960222474f, -0.70710678118654752440f, -0.83146961230254523708f,
            -0.92387953251128675613f, -0.98078528040323044913f };
        constexpr float WSI[16] = {
            0.f, 0.19509032201612826785f, 0.38268343236508977173f, 0.55557023301960222474f,
            0.70710678118654752440f, 0.83146961230254523708f, 0.92387953251128675613f,
            0.98078528040323044913f, 1.f, 0.98078528040323044913f, 0.92387953251128675613f,
            0.83146961230254523708f, 0.70710678118654752440f, 0.55557023301960222474f,
            0.38268343236508977173f, 0.19509032201612826785f };
        const float scale = 1.0f / (float)N_FFT;
        float* out0 = out + (size_t)(2 * row) * T_LEN;
        float* out1 = out + (size_t)(2 * row + 1) * T_LEN;
#pragma unroll
        for (int p = 0; p < 16; p++) {
            float2 o = (p == 0) ? bO[0] : cmul(bO[p], make_float2(WCI[p], WSI[p]));
            float2 y = cadd(bE[p], o);
            int n = (16 * p + u) * N2 + n2;        // n1 = 16p+u < 256
            out0[n] = y.x * scale;
            out1[n] = y.y * scale;
        }
    }
}

extern "C" void kernel_launch(void* const* d_in, const int* in_sizes, int n_in,
                              void* d_out, int out_size, void* d_ws, size_t ws_size,
                              hipStream_t stream) {
    const float* x    = (const float*)d_in[0];
    const float* filt = (const float*)d_in[1];
    float* out = (float*)d_out;

    h2* buf = (h2*)d_ws;                                                        // 67 MB
    float2* G = (float2*)((char*)d_ws + (size_t)CB * N_FFT * sizeof(h2));       // 1 MB

    fwd_cols<false><<<dim3(16, 1), 256, 0, stream>>>(filt, nullptr, 0LL, (void*)G);
    fwd_rows_g<<<N1 / 8, 128, 0, stream>>>(G);
    fwd_cols<true><<<dim3(16, CB), 256, 0, stream>>>(x, x + T_LEN, (long long)(2 * T_LEN), (void*)buf);
    mid_rows<<<(CB * N1) / 16, 256, 0, stream>>>(buf, G);
    inv_cols<<<dim3(16, CB), 256, 0, stream>>>(buf, out);
}